// Round 6
// baseline (367.718 us; speedup 1.0000x reference)
//
#include <hip/hip_runtime.h>
#include <hip/hip_fp16.h>
#include <math.h>

// ---------------------------------------------------------------------------
// SolventGCN round 12:
//   prep(zero+W-swizzle) -> {p1 || gemm0(unscaled)} -> p3(atomic-base CSR)
//   -> fusedBoth<SRCSCALE>(agg0+gemm1) -> fusedBoth(agg1+gemm2)
//   -> aggBoth(layer2) -> poolDense.
// vs r11: W fragments staged into LDS again (global streaming missed L2 under
// gather pressure: FETCH +9.4MB, +5us/dispatch) -- but staged FROM the
// prep-swizzled buffer (pure coalesced 16B/lane copy); (off,cnt) packed into
// one int2 load per node.
// ---------------------------------------------------------------------------

static inline int cdiv(int a, int b) { return (a + b - 1) / b; }

#define BUCKET_CAP 8192
#define P1_CHUNK   4096

typedef _Float16 v8h __attribute__((ext_vector_type(8)));
typedef float    v4f __attribute__((ext_vector_type(4)));

// ---- proportional block-type interleave ----
__device__ __forceinline__ bool split_grid(int bid, int nMaj, int nMin, int& idx) {
    int T  = nMaj + nMin;
    int g0 = (int)(((long long)bid * nMin) / T);
    int g1 = (int)(((long long)(bid + 1) * nMin) / T);
    if (g1 > g0) { idx = g0; return true; }
    idx = bid - g0;
    return false;
}

// ---- prep: zero bucket fills/cursor + swizzle weights into fragment order ----
// Wz entry (ntl*KS+ks)*64+lane = 8 halves: W[ks*32+(lane>>4)*8+j][ntl*16+(lane&15)]
__device__ void wswz(const float* __restrict__ W, float4* __restrict__ D, int K, int M) {
    int NT = M / 16, KS = K / 32, WENT = NT * KS * 64;
    for (int idx = threadIdx.x; idx < WENT; idx += 256) {
        int lane = idx & 63, rest = idx >> 6;
        int ks = rest % KS, ntl = rest / KS;
        int kbase = ks * 32 + (lane >> 4) * 8;
        int col   = ntl * 16 + (lane & 15);
        union { float4 f4; _Float16 h[8]; } u;
#pragma unroll
        for (int j = 0; j < 8; ++j) u.h[j] = (_Float16)W[(kbase + j) * M + col];
        D[idx] = u.f4;
    }
}

__global__ __launch_bounds__(256) void prep(
        int* __restrict__ bucket_fill, int nbuck, int* __restrict__ cursor,
        const float* __restrict__ Wc0, const float* __restrict__ Wc1, const float* __restrict__ Wc2,
        const float* __restrict__ Ws0, const float* __restrict__ Ws1, const float* __restrict__ Ws2,
        float4* __restrict__ WzC0, float4* __restrict__ WzC1, float4* __restrict__ WzC2,
        float4* __restrict__ WzS0, float4* __restrict__ WzS1, float4* __restrict__ WzS2) {
    int b = blockIdx.x;
    if (b == 0) {
        for (int i = threadIdx.x; i < nbuck; i += 256) bucket_fill[i] = 0;
        if (threadIdx.x == 0) *cursor = 0;
    } else if (b == 1) wswz(Wc0, WzC0, 64, 64);
    else if (b == 2)   wswz(Wc1, WzC1, 64, 64);
    else if (b == 3)   wswz(Wc2, WzC2, 64, 64);
    else if (b == 4)   wswz(Ws0, WzS0, 64, 32);
    else if (b == 5)   wswz(Ws1, WzS1, 32, 32);
    else               wswz(Ws2, WzS2, 32, 32);
}

// ---- pass 1 body: partition edges into buckets (packed) ----
__device__ void p1_body(int bid, const int* __restrict__ c_edge, int Ec,
                        const int* __restrict__ s_edge, int Es,
                        int Nc_pad, int Etot, int nbuck,
                        int* __restrict__ bucket_fill,
                        unsigned* __restrict__ pk, char* smem) {
    unsigned*       wbuf = (unsigned*)smem;                 // 16384 B
    unsigned short* bbuf = (unsigned short*)(smem + 16384); // 8192 B
    int*            hist = (int*)(smem + 24576);            // 2048 B
    int e0 = bid * P1_CHUNK;
    int n  = Etot - e0;
    if (n > P1_CHUNK) n = P1_CHUNK;
    for (int i = threadIdx.x; i < nbuck; i += 256) hist[i] = 0;
    __syncthreads();
    for (int i = threadIdx.x; i < n; i += 256) {
        int e = e0 + i, src, g;
        if (e < Ec) { src = c_edge[e]; g = c_edge[Ec + e]; }
        else        { int e2 = e - Ec; src = s_edge[e2]; g = Nc_pad + s_edge[Es + e2]; }
        int b   = g >> 9;
        wbuf[i] = ((unsigned)(g & 511) << 17) | (unsigned)src;
        bbuf[i] = (unsigned short)b;
        atomicAdd(&hist[b], 1);
    }
    __syncthreads();
    for (int i = threadIdx.x; i < nbuck; i += 256) {
        int h = hist[i];
        hist[i] = h ? atomicAdd(&bucket_fill[i], h) : 0;
    }
    __syncthreads();
    for (int i = threadIdx.x; i < n; i += 256) {
        int b    = bbuf[i];
        int slot = atomicAdd(&hist[b], 1);
        if (slot < BUCKET_CAP) pk[(size_t)b * BUCKET_CAP + slot] = wbuf[i];
    }
}

// ---- pass 3: per-bucket CSR build; base self-assigned via atomic cursor ----
__global__ __launch_bounds__(512) void p3_build(const unsigned* __restrict__ pk,
                                                const int* __restrict__ fillarr,
                                                int* __restrict__ cursor,
                                                int2* __restrict__ oc_all,
                                                float* __restrict__ dinv,
                                                int* __restrict__ csr) {
    __shared__ int sh[512];
    __shared__ int base_sh;
    int b    = blockIdx.x;
    int fill = fillarr[b];
    if (fill > BUCKET_CAP) fill = BUCKET_CAP;
    const unsigned* reg = pk + (size_t)b * BUCKET_CAP;
    sh[threadIdx.x] = 0;
    __syncthreads();
    for (int i = threadIdx.x; i < fill; i += 512) atomicAdd(&sh[reg[i] >> 17], 1);
    __syncthreads();
    int cnt = sh[threadIdx.x];
    for (int ofs = 1; ofs < 512; ofs <<= 1) {   // inclusive scan
        int t = (threadIdx.x >= ofs) ? sh[threadIdx.x - ofs] : 0;
        __syncthreads();
        sh[threadIdx.x] += t;
        __syncthreads();
    }
    if (threadIdx.x == 511) base_sh = atomicAdd(cursor, sh[511]);
    __syncthreads();
    int excl = sh[threadIdx.x] - cnt;
    int base = base_sh;
    int node = b * 512 + threadIdx.x;           // padded-global id
    oc_all[node] = make_int2(base + excl, cnt);
    dinv[node]   = rsqrtf((float)(cnt + 1));    // +1 self-loop
    __syncthreads();
    sh[threadIdx.x] = excl;   // cursor for CSR scatter
    __syncthreads();
    for (int i = threadIdx.x; i < fill; i += 512) {
        unsigned w    = reg[i];
        int      slot = atomicAdd(&sh[w >> 17], 1);
        csr[base + slot] = (int)(w & 0x1FFFFu);
    }
}

// ---- MFMA GEMM body: H[N][M] = fp16(X @ W); W staged LDS<-swizzled global ----
template <int K, int M, typename TIN>
__device__ void gemm_mfma(int bid, const TIN* __restrict__ X, const float4* __restrict__ WzG,
                          __half* __restrict__ H, int N, char* smem_) {
    constexpr int RB = 64;        // rows per block
    constexpr int KP = K + 8;     // padded LDS row (halves)
    constexpr int NT = M / 16;    // 16-col tiles
    constexpr int KS = K / 32;    // 32-k steps
    constexpr int WENT = NT * KS * 64;
    _Float16* Xh = (_Float16*)smem_;                    // [RB][KP]
    float4*   Wl = (float4*)(smem_ + RB * KP * 2);      // [WENT]
    const int t    = threadIdx.x;
    const int row0 = bid * RB;

    for (int idx = t; idx < WENT; idx += 256) Wl[idx] = WzG[idx];  // coalesced copy

    if constexpr (sizeof(TIN) == 4) {
        constexpr int NI = RB * K / 4;
        for (int idx = t; idx < NI; idx += 256) {
            int row = idx / (K / 4), k4 = idx % (K / 4);
            int gr = row0 + row;
            float4 v = make_float4(0.f, 0.f, 0.f, 0.f);
            if (gr < N) v = *(const float4*)((const float*)X + (size_t)gr * K + k4 * 4);
            union { float2 f2; _Float16 h[4]; } u;
            u.h[0] = (_Float16)v.x; u.h[1] = (_Float16)v.y;
            u.h[2] = (_Float16)v.z; u.h[3] = (_Float16)v.w;
            *(float2*)(Xh + row * KP + k4 * 4) = u.f2;
        }
    } else {
        constexpr int NI = RB * K / 8;
        for (int idx = t; idx < NI; idx += 256) {
            int row = idx / (K / 8), k8 = idx % (K / 8);
            int gr = row0 + row;
            float4 v = make_float4(0.f, 0.f, 0.f, 0.f);
            if (gr < N) v = *(const float4*)((const __half*)X + (size_t)gr * K + k8 * 8);
            *(float4*)(Xh + row * KP + k8 * 8) = v;
        }
    }
    __syncthreads();

    const int wave = t >> 6, lane = t & 63;
    const int quad = lane >> 4, nl = lane & 15;
    const int rowA = wave * 16 + nl;

    v4f acc[NT];
#pragma unroll
    for (int i = 0; i < NT; ++i) acc[i] = (v4f){0.f, 0.f, 0.f, 0.f};

#pragma unroll
    for (int ks = 0; ks < KS; ++ks) {
        v8h a = *(const v8h*)(Xh + rowA * KP + ks * 32 + quad * 8);
#pragma unroll
        for (int ntl = 0; ntl < NT; ++ntl) {
            v8h b = *(const v8h*)(Wl + (ntl * KS + ks) * 64 + lane);
            acc[ntl] = __builtin_amdgcn_mfma_f32_16x16x32_f16(a, b, acc[ntl], 0, 0, 0);
        }
    }

#pragma unroll
    for (int r = 0; r < 4; ++r) {
        int gr = row0 + wave * 16 + quad * 4 + r;
        if (gr < N) {
#pragma unroll
            for (int ntl = 0; ntl < NT; ++ntl)
                H[(size_t)gr * M + ntl * 16 + nl] = __float2half(acc[ntl][r]);
        }
    }
}

// ---- half helpers ----
__device__ __forceinline__ float4 load4h(const float2* __restrict__ base, size_t idx) {
    float2 r = base[idx];
    union { float2 f2; __half2 h2[2]; } u;
    u.f2 = r;
    float2 a = __half22float2(u.h2[0]);
    float2 b = __half22float2(u.h2[1]);
    return make_float4(a.x, a.y, b.x, b.y);
}

__device__ __forceinline__ void cvt8(float4 r, float* __restrict__ o) {
    union { float4 f4; __half2 h2[4]; } u;
    u.f4 = r;
    float2 p;
    p = __half22float2(u.h2[0]); o[0] = p.x; o[1] = p.y;
    p = __half22float2(u.h2[1]); o[2] = p.x; o[3] = p.y;
    p = __half22float2(u.h2[2]); o[4] = p.x; o[5] = p.y;
    p = __half22float2(u.h2[3]); o[6] = p.x; o[7] = p.y;
}

// ---- gather core (fused layers): 16B/lane, raw float4 neighbor rows ----
template <int L, bool SRCSCALE>
__device__ void gather_row(const float4* __restrict__ H4, int node, int fq,
                           const int2* __restrict__ oc_g, const int* __restrict__ csr,
                           const float* __restrict__ dinv_g, float* __restrict__ acc) {
    int2 oc = oc_g[node];
    int j0 = oc.x, j1 = oc.x + oc.y;
    {
        float4 r = H4[(size_t)node * L + fq];
        cvt8(r, acc);
        if constexpr (SRCSCALE) {
            float dvs = dinv_g[node];
#pragma unroll
            for (int f = 0; f < 8; ++f) acc[f] *= dvs;
        }
    }
    float a[8];
    int j = j0;
    for (; j + 8 <= j1; j += 8) {
        int s0 = csr[j],     s1 = csr[j + 1], s2 = csr[j + 2], s3 = csr[j + 3];
        int s4 = csr[j + 4], s5 = csr[j + 5], s6 = csr[j + 6], s7 = csr[j + 7];
        float4 r0 = H4[(size_t)s0 * L + fq];
        float4 r1 = H4[(size_t)s1 * L + fq];
        float4 r2 = H4[(size_t)s2 * L + fq];
        float4 r3 = H4[(size_t)s3 * L + fq];
        float4 r4 = H4[(size_t)s4 * L + fq];
        float4 r5 = H4[(size_t)s5 * L + fq];
        float4 r6 = H4[(size_t)s6 * L + fq];
        float4 r7 = H4[(size_t)s7 * L + fq];
        if constexpr (SRCSCALE) {
            float d0 = dinv_g[s0], d1 = dinv_g[s1], d2 = dinv_g[s2], d3 = dinv_g[s3];
            float d4 = dinv_g[s4], d5 = dinv_g[s5], d6 = dinv_g[s6], d7 = dinv_g[s7];
            cvt8(r0, a);
#pragma unroll
            for (int f = 0; f < 8; ++f) acc[f] = fmaf(a[f], d0, acc[f]);
            cvt8(r1, a);
#pragma unroll
            for (int f = 0; f < 8; ++f) acc[f] = fmaf(a[f], d1, acc[f]);
            cvt8(r2, a);
#pragma unroll
            for (int f = 0; f < 8; ++f) acc[f] = fmaf(a[f], d2, acc[f]);
            cvt8(r3, a);
#pragma unroll
            for (int f = 0; f < 8; ++f) acc[f] = fmaf(a[f], d3, acc[f]);
            cvt8(r4, a);
#pragma unroll
            for (int f = 0; f < 8; ++f) acc[f] = fmaf(a[f], d4, acc[f]);
            cvt8(r5, a);
#pragma unroll
            for (int f = 0; f < 8; ++f) acc[f] = fmaf(a[f], d5, acc[f]);
            cvt8(r6, a);
#pragma unroll
            for (int f = 0; f < 8; ++f) acc[f] = fmaf(a[f], d6, acc[f]);
            cvt8(r7, a);
#pragma unroll
            for (int f = 0; f < 8; ++f) acc[f] = fmaf(a[f], d7, acc[f]);
        } else {
            cvt8(r0, a);
#pragma unroll
            for (int f = 0; f < 8; ++f) acc[f] += a[f];
            cvt8(r1, a);
#pragma unroll
            for (int f = 0; f < 8; ++f) acc[f] += a[f];
            cvt8(r2, a);
#pragma unroll
            for (int f = 0; f < 8; ++f) acc[f] += a[f];
            cvt8(r3, a);
#pragma unroll
            for (int f = 0; f < 8; ++f) acc[f] += a[f];
            cvt8(r4, a);
#pragma unroll
            for (int f = 0; f < 8; ++f) acc[f] += a[f];
            cvt8(r5, a);
#pragma unroll
            for (int f = 0; f < 8; ++f) acc[f] += a[f];
            cvt8(r6, a);
#pragma unroll
            for (int f = 0; f < 8; ++f) acc[f] += a[f];
            cvt8(r7, a);
#pragma unroll
            for (int f = 0; f < 8; ++f) acc[f] += a[f];
        }
    }
    for (; j + 4 <= j1; j += 4) {
        int s0 = csr[j], s1 = csr[j + 1], s2 = csr[j + 2], s3 = csr[j + 3];
        float4 r0 = H4[(size_t)s0 * L + fq];
        float4 r1 = H4[(size_t)s1 * L + fq];
        float4 r2 = H4[(size_t)s2 * L + fq];
        float4 r3 = H4[(size_t)s3 * L + fq];
        if constexpr (SRCSCALE) {
            float d0 = dinv_g[s0], d1 = dinv_g[s1], d2 = dinv_g[s2], d3 = dinv_g[s3];
            cvt8(r0, a);
#pragma unroll
            for (int f = 0; f < 8; ++f) acc[f] = fmaf(a[f], d0, acc[f]);
            cvt8(r1, a);
#pragma unroll
            for (int f = 0; f < 8; ++f) acc[f] = fmaf(a[f], d1, acc[f]);
            cvt8(r2, a);
#pragma unroll
            for (int f = 0; f < 8; ++f) acc[f] = fmaf(a[f], d2, acc[f]);
            cvt8(r3, a);
#pragma unroll
            for (int f = 0; f < 8; ++f) acc[f] = fmaf(a[f], d3, acc[f]);
        } else {
            cvt8(r0, a);
#pragma unroll
            for (int f = 0; f < 8; ++f) acc[f] += a[f];
            cvt8(r1, a);
#pragma unroll
            for (int f = 0; f < 8; ++f) acc[f] += a[f];
            cvt8(r2, a);
#pragma unroll
            for (int f = 0; f < 8; ++f) acc[f] += a[f];
            cvt8(r3, a);
#pragma unroll
            for (int f = 0; f < 8; ++f) acc[f] += a[f];
        }
    }
    for (; j < j1; ++j) {
        int s0 = csr[j];
        float4 r0 = H4[(size_t)s0 * L + fq];
        cvt8(r0, a);
        if constexpr (SRCSCALE) {
            float d0 = dinv_g[s0];
#pragma unroll
            for (int f = 0; f < 8; ++f) acc[f] = fmaf(a[f], d0, acc[f]);
        } else {
#pragma unroll
            for (int f = 0; f < 8; ++f) acc[f] += a[f];
        }
    }
}

// ---- fused agg_k -> gemm_{k+1}: block = 64 nodes of one side ----
template <int MF, bool SRCSCALE>   // MF = feature width (c:64, s:32)
__device__ void fused_agg_gemm(int bid, const __half* __restrict__ Hin,
                               const int2* __restrict__ oc_g, const int* __restrict__ csr,
                               const float* __restrict__ dinv_g, const float* __restrict__ b,
                               const float4* __restrict__ WzG, __half* __restrict__ Hout,
                               int N, char* smem_) {
    constexpr int KP = MF + 8;
    constexpr int NT = MF / 16;
    constexpr int KS = MF / 32;
    constexpr int WENT = NT * KS * 64;
    _Float16* Xh = (_Float16*)smem_;                    // [64][KP]
    float4*   Wl = (float4*)(smem_ + 64 * KP * 2);      // [WENT]
    const int t = threadIdx.x;

    // ---- stage W fragments (coalesced, L2-hot, latency hidden by gather) ----
    for (int idx = t; idx < WENT; idx += 256) Wl[idx] = WzG[idx];

    // ---- agg phase: 16B/lane, L lanes per node ----
    constexpr int L      = MF / 8;         // c:8, s:4
    constexpr int NPW    = 64 / L;         // c:8, s:16
    constexpr int PASSES = 64 / (4 * NPW); // c:2, s:1
    const int lane = t & 63, wave = t >> 6;
    const int fq = lane & (L - 1), sub = lane / L;
    const float4* H4 = (const float4*)Hin;
    const float4* b4 = (const float4*)b;
    float bb[8];
    {
        float4 b0 = b4[fq * 2], b1 = b4[fq * 2 + 1];
        bb[0] = b0.x; bb[1] = b0.y; bb[2] = b0.z; bb[3] = b0.w;
        bb[4] = b1.x; bb[5] = b1.y; bb[6] = b1.z; bb[7] = b1.w;
    }
#pragma unroll
    for (int pass = 0; pass < PASSES; ++pass) {
        int ln   = (pass * 4 + wave) * NPW + sub;   // local row 0..63
        int node = bid * 64 + ln;
        if (node < N) {
            float acc[8];
            gather_row<L, SRCSCALE>(H4, node, fq, oc_g, csr, dinv_g, acc);
            float dv = dinv_g[node];
            union { float4 f4; __half2 h2[4]; } o;
#pragma unroll
            for (int p2 = 0; p2 < 4; ++p2) {
                float vx = dv * acc[2 * p2]     + bb[2 * p2];
                float vy = dv * acc[2 * p2 + 1] + bb[2 * p2 + 1];
                o.h2[p2] = __floats2half2_rn(vx > 0.f ? vx : 0.f, vy > 0.f ? vy : 0.f);
            }
            *(float4*)(Xh + ln * KP + fq * 8) = o.f4;
        } else {
            *(float4*)(Xh + ln * KP + fq * 8) = make_float4(0.f, 0.f, 0.f, 0.f);
        }
    }
    __syncthreads();

    // ---- MFMA phase (A from Xh, B from Wl; both LDS) ----
    const int quad = lane >> 4, nl = lane & 15;
    const int rowA = wave * 16 + nl;
    v4f acc2[NT];
#pragma unroll
    for (int i = 0; i < NT; ++i) acc2[i] = (v4f){0.f, 0.f, 0.f, 0.f};
#pragma unroll
    for (int ks = 0; ks < KS; ++ks) {
        v8h av = *(const v8h*)(Xh + rowA * KP + ks * 32 + quad * 8);
#pragma unroll
        for (int ntl = 0; ntl < NT; ++ntl) {
            v8h bv = *(const v8h*)(Wl + (ntl * KS + ks) * 64 + lane);
            acc2[ntl] = __builtin_amdgcn_mfma_f32_16x16x32_f16(av, bv, acc2[ntl], 0, 0, 0);
        }
    }
#pragma unroll
    for (int r = 0; r < 4; ++r) {
        int gr = bid * 64 + wave * 16 + quad * 4 + r;
        if (gr < N) {
            float dv = dinv_g[gr];
#pragma unroll
            for (int ntl = 0; ntl < NT; ++ntl)
                Hout[(size_t)gr * MF + ntl * 16 + nl] = __float2half(acc2[ntl][r] * dv);
        }
    }
}

// ---- plain aggregate (final layer, node-partitioned, r7-proven) ----
template <int M>
__device__ void agg_body(int bid, const __half* __restrict__ H,
                         const int2* __restrict__ oc_g,
                         const int* __restrict__ csr,
                         const float* __restrict__ dinv_g,
                         const float* __restrict__ b,
                         __half* __restrict__ out, int Nloc) {
    constexpr int L   = M / 4;   // lanes per node (4 halves each)
    constexpr int NPW = 64 / L;  // nodes per wave
    int lane = threadIdx.x & 63;
    int wave = threadIdx.x >> 6;
    int fq   = lane & (L - 1);
    int sub  = lane / L;
    int node = (bid * 4 + wave) * NPW + sub;
    if (node >= Nloc) return;
    const float2* H4 = (const float2*)H;
    int2 oc = oc_g[node];
    int j0 = oc.x, j1 = oc.x + oc.y;
    float4 acc = load4h(H4, (size_t)node * L + fq);  // self-loop
    int j = j0;
    for (; j + 8 <= j1; j += 8) {
        int s0 = csr[j],     s1 = csr[j + 1], s2 = csr[j + 2], s3 = csr[j + 3];
        int s4 = csr[j + 4], s5 = csr[j + 5], s6 = csr[j + 6], s7 = csr[j + 7];
        float4 a0 = load4h(H4, (size_t)s0 * L + fq);
        float4 a1 = load4h(H4, (size_t)s1 * L + fq);
        float4 a2 = load4h(H4, (size_t)s2 * L + fq);
        float4 a3 = load4h(H4, (size_t)s3 * L + fq);
        float4 a4 = load4h(H4, (size_t)s4 * L + fq);
        float4 a5 = load4h(H4, (size_t)s5 * L + fq);
        float4 a6 = load4h(H4, (size_t)s6 * L + fq);
        float4 a7 = load4h(H4, (size_t)s7 * L + fq);
        acc.x += (a0.x + a1.x + a2.x + a3.x) + (a4.x + a5.x + a6.x + a7.x);
        acc.y += (a0.y + a1.y + a2.y + a3.y) + (a4.y + a5.y + a6.y + a7.y);
        acc.z += (a0.z + a1.z + a2.z + a3.z) + (a4.z + a5.z + a6.z + a7.z);
        acc.w += (a0.w + a1.w + a2.w + a3.w) + (a4.w + a5.w + a6.w + a7.w);
    }
    for (; j + 4 <= j1; j += 4) {
        int s0 = csr[j], s1 = csr[j + 1], s2 = csr[j + 2], s3 = csr[j + 3];
        float4 a0 = load4h(H4, (size_t)s0 * L + fq);
        float4 a1 = load4h(H4, (size_t)s1 * L + fq);
        float4 a2 = load4h(H4, (size_t)s2 * L + fq);
        float4 a3 = load4h(H4, (size_t)s3 * L + fq);
        acc.x += a0.x + a1.x + a2.x + a3.x;
        acc.y += a0.y + a1.y + a2.y + a3.y;
        acc.z += a0.z + a1.z + a2.z + a3.z;
        acc.w += a0.w + a1.w + a2.w + a3.w;
    }
    for (; j < j1; ++j) {
        float4 a = load4h(H4, (size_t)csr[j] * L + fq);
        acc.x += a.x; acc.y += a.y; acc.z += a.z; acc.w += a.w;
    }
    float  dv = dinv_g[node];
    float4 bb = ((const float4*)b)[fq];
    float  vx = dv * acc.x + bb.x;
    float  vy = dv * acc.y + bb.y;
    float  vz = dv * acc.z + bb.z;
    float  vw = dv * acc.w + bb.w;
    union { float2 f2; __half2 h2[2]; } o;
    o.h2[0] = __floats2half2_rn(vx > 0.f ? vx : 0.f, vy > 0.f ? vy : 0.f);
    o.h2[1] = __floats2half2_rn(vz > 0.f ? vz : 0.f, vw > 0.f ? vw : 0.f);
    ((float2*)out)[(size_t)node * L + fq] = o.f2;
}

// ---- merged: CSR pass 1 || layer-0 GEMM (unscaled output) ----
__global__ __launch_bounds__(256) void p1_gemm0(
        const int* __restrict__ c_edge, int Ec, const int* __restrict__ s_edge, int Es,
        int Nc_pad, int Etot, int nbuck,
        int* __restrict__ bucket_fill, unsigned* __restrict__ pk,
        const float* __restrict__ Xc, const float4* __restrict__ WzC0, __half* __restrict__ cH, int Nc,
        const float* __restrict__ Xs, const float4* __restrict__ WzS0, __half* __restrict__ sH, int Ns,
        int nP1, int nGemC, int nGemS) {
    __shared__ __align__(16) char smem[26624];
    int idx;
    if (split_grid(blockIdx.x, nGemC + nGemS, nP1, idx)) {
        p1_body(idx, c_edge, Ec, s_edge, Es, Nc_pad, Etot, nbuck, bucket_fill, pk, smem);
    } else if (idx < nGemC) {
        gemm_mfma<64, 64, float>(idx, Xc, WzC0, cH, Nc, smem);
    } else {
        gemm_mfma<64, 32, float>(idx - nGemC, Xs, WzS0, sH, Ns, smem);
    }
}

// ---- fused agg+gemm, both sides per dispatch ----
template <bool SRCSCALE>
__global__ __launch_bounds__(256) void fusedBoth(
        const __half* __restrict__ cHin, __half* __restrict__ cHout,
        const float4* __restrict__ WzC, const float* __restrict__ bc,
        const __half* __restrict__ sHin, __half* __restrict__ sHout,
        const float4* __restrict__ WzS, const float* __restrict__ bs,
        const int2* __restrict__ oc_all, const int* __restrict__ csr_all,
        const float* __restrict__ dinv_all,
        int Nc, int Ns, int Nc_pad, int nbC) {
    __shared__ __align__(16) char smem[17408];
    if (blockIdx.x < nbC)
        fused_agg_gemm<64, SRCSCALE>(blockIdx.x, cHin, oc_all, csr_all,
                                     dinv_all, bc, WzC, cHout, Nc, smem);
    else
        fused_agg_gemm<32, SRCSCALE>(blockIdx.x - nbC, sHin, oc_all + Nc_pad, csr_all,
                                     dinv_all + Nc_pad, bs, WzS, sHout, Ns, smem);
}

// ---- final aggregation, both sides per dispatch (node-partitioned) ----
__global__ __launch_bounds__(256) void aggBoth(const __half* __restrict__ cH, const __half* __restrict__ sH,
                                               const int2* __restrict__ oc_all,
                                               const int* __restrict__ csr_all,
                                               const float* __restrict__ dinv_all,
                                               const float* __restrict__ bc, const float* __restrict__ bs,
                                               __half* __restrict__ outc, __half* __restrict__ outs,
                                               int Nc, int Ns, int Nc_pad, int nbC) {
    if (blockIdx.x < nbC)
        agg_body<64>(blockIdx.x, cH, oc_all, csr_all, dinv_all, bc, outc, Nc);
    else
        agg_body<32>(blockIdx.x - nbC, sH, oc_all + Nc_pad, csr_all,
                     dinv_all + Nc_pad, bs, outs, Ns);
}

// ---- fused pooling + MLP head (single kernel, 256 threads) ----
__device__ __forceinline__ int lbound(const int* __restrict__ a, int n, int key) {
    int lo = 0, hi = n;
    while (lo < hi) {
        int mid = (lo + hi) >> 1;
        if (a[mid] < key) lo = mid + 1; else hi = mid;
    }
    return lo;
}

__global__ __launch_bounds__(256) void poolDense(const __half* __restrict__ cX, const int* __restrict__ c_batch, int Nc,
                                                 const __half* __restrict__ sX, const int* __restrict__ s_batch, int Ns,
                                                 const float* __restrict__ Wd, const float* __restrict__ bd,
                                                 const float* __restrict__ Wo, const float* __restrict__ bo,
                                                 float* __restrict__ outv, float* __restrict__ embed) {
    __shared__ float e[192];
    __shared__ float red[512];
    __shared__ float rs[128];
    int g = blockIdx.x, t = threadIdx.x;
    int clo = lbound(c_batch, Nc, g), chi = lbound(c_batch, Nc, g + 1);
    {   // c-pool: 64 features x 4 row-groups
        int f = t & 63, grp = t >> 6;
        float mx = 0.f, sm = 0.f;
        for (int i = clo + grp; i < chi; i += 4) {
            float v = __half2float(cX[(size_t)i * 64 + f]);
            mx = fmaxf(mx, v); sm += v;
        }
        red[grp * 64 + f]       = mx;
        red[256 + grp * 64 + f] = sm;
    }
    __syncthreads();
    if (t < 64) {
        float m = fmaxf(fmaxf(red[t], red[64 + t]), fmaxf(red[128 + t], red[192 + t]));
        float s = (red[256 + t] + red[320 + t]) + (red[384 + t] + red[448 + t]);
        int cn = chi - clo;
        e[t]      = m;
        e[64 + t] = s / (float)(cn > 0 ? cn : 1);
    }
    __syncthreads();
    int slo = lbound(s_batch, Ns, g), shi = lbound(s_batch, Ns, g + 1);
    {   // s-pool: 32 features x 8 row-groups
        int f = t & 31, grp = t >> 5;
        float mx = 0.f, sm = 0.f;
        for (int i = slo + grp; i < shi; i += 8) {
            float v = __half2float(sX[(size_t)i * 32 + f]);
            mx = fmaxf(mx, v); sm += v;
        }
        red[grp * 32 + f]       = mx;
        red[256 + grp * 32 + f] = sm;
    }
    __syncthreads();
    if (t < 32) {
        float m = red[t];
        float s = red[256 + t];
#pragma unroll
        for (int grp = 1; grp < 8; ++grp) {
            m  = fmaxf(m, red[grp * 32 + t]);
            s += red[256 + grp * 32 + t];
        }
        int cn = shi - slo;
        e[128 + t] = m;
        e[160 + t] = s / (float)(cn > 0 ? cn : 1);
    }
    __syncthreads();
    if (t < 192) embed[(size_t)g * 192 + t] = e[t];
    if (t < 128) {
        float acc = bd[t];
        for (int k = 0; k < 192; ++k) acc += e[k] * Wd[k * 128 + t];
        float d = acc > 0.f ? acc : 0.f;
        rs[t] = d * Wo[t];
    }
    __syncthreads();
    for (int ofs = 64; ofs > 0; ofs >>= 1) {
        if (t < ofs) rs[t] += rs[t + ofs];
        __syncthreads();
    }
    if (t == 0) outv[g] = rs[0] + bo[0];
}

// ---------------------------------------------------------------------------

extern "C" void kernel_launch(void* const* d_in, const int* in_sizes, int n_in,
                              void* d_out, int out_size, void* d_ws, size_t ws_size,
                              hipStream_t stream) {
    const float* c       = (const float*)d_in[0];
    const int*   c_edge  = (const int*)d_in[1];
    const int*   c_batch = (const int*)d_in[2];
    const float* s       = (const float*)d_in[3];
    const int*   s_edge  = (const int*)d_in[4];
    const int*   s_batch = (const int*)d_in[5];
    const float* Wc0 = (const float*)d_in[6],  *bc0 = (const float*)d_in[7];
    const float* Wc1 = (const float*)d_in[8],  *bc1 = (const float*)d_in[9];
    const float* Wc2 = (const float*)d_in[10], *bc2 = (const float*)d_in[11];
    const float* Ws0 = (const float*)d_in[12], *bs0 = (const float*)d_in[13];
    const float* Ws1 = (const float*)d_in[14], *bs1 = (const float*)d_in[15];
    const float* Ws2 = (const float*)d_in[16], *bs2 = (const float*)d_in[17];
    const float* Wd  = (const float*)d_in[18], *bd  = (const float*)d_in[19];
    const float* Wo  = (const float*)d_in[20], *bo  = (const float*)d_in[21];

    const int Nc = in_sizes[0] / 64;
    const int Ec = in_sizes[1] / 2;
    const int Ns = in_sizes[3] / 64;
    const int Es = in_sizes[4] / 2;
    const int G  = out_size / 193;  // 2048
    const int Nc_pad   = cdiv(Nc, 512) * 512;
    const int Ns_pad   = cdiv(Ns, 512) * 512;
    const int Ntot_pad = Nc_pad + Ns_pad;
    const int Etot     = Ec + Es;
    const int nbuck    = Ntot_pad >> 9;

    // ---- workspace carve ----
    char* p = (char*)d_ws;
    auto  alloc = [&](size_t bytes) -> void* {
        void* r = (void*)p;
        p += (bytes + 255) & ~(size_t)255;
        return r;
    };
    int*      bucket_fill = (int*)alloc(512 * 4);
    int*      cursor      = (int*)alloc(256);
    unsigned* pk          = (unsigned*)alloc((size_t)nbuck * BUCKET_CAP * 4);
    int2*     oc_all      = (int2*)alloc((size_t)Ntot_pad * 8);
    int*      csr_all     = (int*)alloc((size_t)Etot * 4);
    float*    dinv_all    = (float*)alloc((size_t)Ntot_pad * 4);
    float4*   WzC0        = (float4*)alloc(8192);
    float4*   WzC1        = (float4*)alloc(8192);
    float4*   WzC2        = (float4*)alloc(8192);
    float4*   WzS0        = (float4*)alloc(4096);
    float4*   WzS1        = (float4*)alloc(2048);
    float4*   WzS2        = (float4*)alloc(2048);
    __half*   cHa         = (__half*)alloc((size_t)Nc * 64 * 2);
    __half*   cHb         = (__half*)alloc((size_t)Nc * 64 * 2);
    __half*   sHa         = (__half*)alloc((size_t)Ns * 32 * 2);
    __half*   sHb         = (__half*)alloc((size_t)Ns * 32 * 2);

    float* outv  = (float*)d_out;  // [G]
    float* embed = outv + G;       // [G][192]

    const int nbGmC = cdiv(Nc, 64), nbGmS = cdiv(Ns, 64);
    const int nbFC  = cdiv(Nc, 64), nbFS  = cdiv(Ns, 64);
    const int nbAgC = Nc_pad / 16,  nbAgS = Ns_pad / 32;
    const int nP1   = cdiv(Etot, P1_CHUNK);

    // 1) prep: zero fills/cursor + swizzle all weights into fragment order
    prep<<<7, 256, 0, stream>>>(bucket_fill, nbuck, cursor,
                                Wc0, Wc1, Wc2, Ws0, Ws1, Ws2,
                                WzC0, WzC1, WzC2, WzS0, WzS1, WzS2);

    // 2) CSR pass 1 || layer-0 GEMM (stores raw XW, no dinv yet)
    p1_gemm0<<<nP1 + nbGmC + nbGmS, 256, 0, stream>>>(
        c_edge, Ec, s_edge, Es, Nc_pad, Etot, nbuck, bucket_fill, pk,
        c, WzC0, cHa, Nc, s, WzS0, sHa, Ns, nP1, nbGmC, nbGmS);

    // 3) CSR build (per-bucket, base via atomic cursor)
    p3_build<<<nbuck, 512, 0, stream>>>(pk, bucket_fill, cursor,
                                        oc_all, dinv_all, csr_all);

    // 4) fused agg0+gemm1 (per-source dinv scaling for raw layer-0 rows)
    fusedBoth<true><<<nbFC + nbFS, 256, 0, stream>>>(
        cHa, cHb, WzC1, bc0, sHa, sHb, WzS1, bs0,
        oc_all, csr_all, dinv_all, Nc, Ns, Nc_pad, nbFC);
    // 5) fused agg1+gemm2
    fusedBoth<false><<<nbFC + nbFS, 256, 0, stream>>>(
        cHb, cHa, WzC2, bc1, sHb, sHa, WzS2, bs1,
        oc_all, csr_all, dinv_all, Nc, Ns, Nc_pad, nbFC);

    // 6) final aggregation (node-partitioned, both sides) -> cHb/sHb
    aggBoth<<<nbAgC + nbAgS, 256, 0, stream>>>(cHa, sHa, oc_all, csr_all, dinv_all,
                                               bc2, bs2, cHb, sHb, Nc, Ns, Nc_pad, nbAgC);

    // 7) fused pooling + MLP
    poolDense<<<G, 256, 0, stream>>>(cHb, c_batch, Nc, sHb, s_batch, Ns,
                                     Wd, bd, Wo, bo, outv, embed);
}

// Round 7
// 354.540 us; speedup vs baseline: 1.0372x; 1.0372x over previous
//
#include <hip/hip_runtime.h>
#include <hip/hip_fp16.h>
#include <math.h>

// ---------------------------------------------------------------------------
// SolventGCN round 13: revert to round-9 config (best measured, 355.5us) +
// vectorized poolDense loads.
//   CSR build -> gemmBoth0 -> fusedBoth(agg0+gemm1) -> fusedBoth(agg1+gemm2)
//   -> aggBoth(layer2) -> poolDense(8B/lane pooling + MLP).
// r10-r12 deltas (per-graph pool, p1+gemm0 merge, W pre-swizzle, atomic-base
// CSR) all measured net-negative -> dropped.
// ---------------------------------------------------------------------------

static inline int cdiv(int a, int b) { return (a + b - 1) / b; }

#define BUCKET_CAP 8192
#define P1_CHUNK   4096

typedef _Float16 v8h __attribute__((ext_vector_type(8)));
typedef float    v4f __attribute__((ext_vector_type(4)));

__global__ void zero_int(int* __restrict__ p, int n) {
    int i = blockIdx.x * blockDim.x + threadIdx.x;
    if (i < n) p[i] = 0;
}

// ---- pass 1: partition edges into buckets (packed) ----
__global__ __launch_bounds__(256) void p1_partition(const int* __restrict__ c_edge, int Ec,
                                                    const int* __restrict__ s_edge, int Es,
                                                    int Nc_pad, int Etot, int nbuck,
                                                    int* __restrict__ bucket_fill,
                                                    unsigned* __restrict__ pk) {
    __shared__ unsigned       wbuf[P1_CHUNK];
    __shared__ unsigned short bbuf[P1_CHUNK];
    __shared__ int            hist[512];
    int e0 = blockIdx.x * P1_CHUNK;
    int n  = Etot - e0;
    if (n > P1_CHUNK) n = P1_CHUNK;
    for (int i = threadIdx.x; i < nbuck; i += 256) hist[i] = 0;
    __syncthreads();
    for (int i = threadIdx.x; i < n; i += 256) {
        int e = e0 + i, src, g;
        if (e < Ec) { src = c_edge[e]; g = c_edge[Ec + e]; }
        else        { int e2 = e - Ec; src = s_edge[e2]; g = Nc_pad + s_edge[Es + e2]; }
        int b   = g >> 9;
        wbuf[i] = ((unsigned)(g & 511) << 17) | (unsigned)src;
        bbuf[i] = (unsigned short)b;
        atomicAdd(&hist[b], 1);
    }
    __syncthreads();
    for (int i = threadIdx.x; i < nbuck; i += 256) {
        int h = hist[i];
        hist[i] = h ? atomicAdd(&bucket_fill[i], h) : 0;
    }
    __syncthreads();
    for (int i = threadIdx.x; i < n; i += 256) {
        int b    = bbuf[i];
        int slot = atomicAdd(&hist[b], 1);
        if (slot < BUCKET_CAP) pk[(size_t)b * BUCKET_CAP + slot] = wbuf[i];
    }
}

// ---- pass 2: exclusive scan of bucket fills ----
__global__ __launch_bounds__(512) void p2_scanbuckets(const int* __restrict__ fill, int nbuck,
                                                      int* __restrict__ basearr,
                                                      int* __restrict__ off_all, int Ntot_pad, int Etot) {
    __shared__ int sh[512];
    int v = (threadIdx.x < nbuck) ? fill[threadIdx.x] : 0;
    sh[threadIdx.x] = v;
    __syncthreads();
    for (int ofs = 1; ofs < 512; ofs <<= 1) {
        int t = (threadIdx.x >= ofs) ? sh[threadIdx.x - ofs] : 0;
        __syncthreads();
        sh[threadIdx.x] += t;
        __syncthreads();
    }
    if (threadIdx.x < nbuck) basearr[threadIdx.x] = sh[threadIdx.x] - v;
    if (threadIdx.x == 0) off_all[Ntot_pad] = Etot;
}

// ---- pass 3: per-bucket CSR build (all per-edge atomics in LDS) ----
__global__ __launch_bounds__(512) void p3_build(const unsigned* __restrict__ pk,
                                                const int* __restrict__ fillarr,
                                                const int* __restrict__ basearr,
                                                int* __restrict__ off_all,
                                                float* __restrict__ dinv,
                                                int* __restrict__ csr) {
    __shared__ int sh[512];
    int b    = blockIdx.x;
    int fill = fillarr[b];
    if (fill > BUCKET_CAP) fill = BUCKET_CAP;
    int base = basearr[b];
    const unsigned* reg = pk + (size_t)b * BUCKET_CAP;
    sh[threadIdx.x] = 0;
    __syncthreads();
    for (int i = threadIdx.x; i < fill; i += 512) atomicAdd(&sh[reg[i] >> 17], 1);
    __syncthreads();
    int cnt = sh[threadIdx.x];
    for (int ofs = 1; ofs < 512; ofs <<= 1) {   // inclusive scan
        int t = (threadIdx.x >= ofs) ? sh[threadIdx.x - ofs] : 0;
        __syncthreads();
        sh[threadIdx.x] += t;
        __syncthreads();
    }
    int excl = sh[threadIdx.x] - cnt;
    int node = b * 512 + threadIdx.x;           // padded-global id
    off_all[node] = base + excl;
    dinv[node]    = rsqrtf((float)(cnt + 1));   // +1 self-loop
    __syncthreads();
    sh[threadIdx.x] = excl;   // cursor for CSR scatter
    __syncthreads();
    for (int i = threadIdx.x; i < fill; i += 512) {
        unsigned w    = reg[i];
        int      slot = atomicAdd(&sh[w >> 17], 1);
        csr[base + slot] = (int)(w & 0x1FFFFu);
    }
}

// ---- MFMA GEMM body: H[N][M] = fp16((X @ W) * dinv[row]) ----
template <int K, int M, typename TIN>
__device__ void gemm_mfma(int bid, const TIN* __restrict__ X, const float* __restrict__ W,
                          const float* __restrict__ dinv, __half* __restrict__ H, int N,
                          char* smem_) {
    constexpr int RB = 64;        // rows per block
    constexpr int KP = K + 8;     // padded LDS row (halves)
    constexpr int NT = M / 16;    // 16-col tiles
    constexpr int KS = K / 32;    // 32-k steps
    _Float16* Xh = (_Float16*)smem_;           // [RB][KP]
    _Float16* Wz = Xh + RB * KP;               // [NT*KS*64][8]
    const int t    = threadIdx.x;
    const int row0 = bid * RB;

    constexpr int WENT = NT * KS * 64;
    for (int idx = t; idx < WENT; idx += 256) {
        int lane = idx & 63, rest = idx >> 6;
        int ks = rest % KS, ntl = rest / KS;
        int kbase = ks * 32 + (lane >> 4) * 8;
        int col   = ntl * 16 + (lane & 15);
        union { float4 f4; _Float16 h[8]; } u;
#pragma unroll
        for (int j = 0; j < 8; ++j) u.h[j] = (_Float16)W[(kbase + j) * M + col];
        *(float4*)(Wz + idx * 8) = u.f4;
    }
    if constexpr (sizeof(TIN) == 4) {
        constexpr int NI = RB * K / 4;
        for (int idx = t; idx < NI; idx += 256) {
            int row = idx / (K / 4), k4 = idx % (K / 4);
            int gr = row0 + row;
            float4 v = make_float4(0.f, 0.f, 0.f, 0.f);
            if (gr < N) v = *(const float4*)((const float*)X + (size_t)gr * K + k4 * 4);
            union { float2 f2; _Float16 h[4]; } u;
            u.h[0] = (_Float16)v.x; u.h[1] = (_Float16)v.y;
            u.h[2] = (_Float16)v.z; u.h[3] = (_Float16)v.w;
            *(float2*)(Xh + row * KP + k4 * 4) = u.f2;
        }
    } else {
        constexpr int NI = RB * K / 8;
        for (int idx = t; idx < NI; idx += 256) {
            int row = idx / (K / 8), k8 = idx % (K / 8);
            int gr = row0 + row;
            float4 v = make_float4(0.f, 0.f, 0.f, 0.f);
            if (gr < N) v = *(const float4*)((const __half*)X + (size_t)gr * K + k8 * 8);
            *(float4*)(Xh + row * KP + k8 * 8) = v;
        }
    }
    __syncthreads();

    const int wave = t >> 6, lane = t & 63;
    const int quad = lane >> 4, nl = lane & 15;
    const int rowA = wave * 16 + nl;

    v4f acc[NT];
#pragma unroll
    for (int i = 0; i < NT; ++i) acc[i] = (v4f){0.f, 0.f, 0.f, 0.f};

#pragma unroll
    for (int ks = 0; ks < KS; ++ks) {
        v8h a = *(const v8h*)(Xh + rowA * KP + ks * 32 + quad * 8);
#pragma unroll
        for (int ntl = 0; ntl < NT; ++ntl) {
            v8h b = *(const v8h*)(Wz + ((ntl * KS + ks) * 64 + lane) * 8);
            acc[ntl] = __builtin_amdgcn_mfma_f32_16x16x32_f16(a, b, acc[ntl], 0, 0, 0);
        }
    }

#pragma unroll
    for (int r = 0; r < 4; ++r) {
        int gr = row0 + wave * 16 + quad * 4 + r;
        if (gr < N) {
            float dv = dinv[gr];
#pragma unroll
            for (int ntl = 0; ntl < NT; ++ntl)
                H[(size_t)gr * M + ntl * 16 + nl] = __float2half(acc[ntl][r] * dv);
        }
    }
}

// ---- half helpers ----
__device__ __forceinline__ float4 load4h(const float2* __restrict__ base, size_t idx) {
    float2 r = base[idx];
    union { float2 f2; __half2 h2[2]; } u;
    u.f2 = r;
    float2 a = __half22float2(u.h2[0]);
    float2 b = __half22float2(u.h2[1]);
    return make_float4(a.x, a.y, b.x, b.y);
}

__device__ __forceinline__ void load8h(const float4* __restrict__ base, size_t idx,
                                       float* __restrict__ o) {
    float4 r = base[idx];
    union { float4 f4; __half2 h2[4]; } u;
    u.f4 = r;
    float2 p0 = __half22float2(u.h2[0]);
    float2 p1 = __half22float2(u.h2[1]);
    float2 p2 = __half22float2(u.h2[2]);
    float2 p3 = __half22float2(u.h2[3]);
    o[0] = p0.x; o[1] = p0.y; o[2] = p1.x; o[3] = p1.y;
    o[4] = p2.x; o[5] = p2.y; o[6] = p3.x; o[7] = p3.y;
}

// ---- fused agg_k -> gemm_{k+1}: block = 64 nodes of one side ----
template <int MF>   // MF = feature width (c:64, s:32); gemm is MF x MF
__device__ void fused_agg_gemm(int bid, const __half* __restrict__ Hin,
                               const int* __restrict__ off_g, const int* __restrict__ csr,
                               const float* __restrict__ dinv_g, const float* __restrict__ b,
                               const float* __restrict__ W, __half* __restrict__ Hout,
                               int N, char* smem_) {
    constexpr int KP = MF + 8;
    constexpr int NT = MF / 16;
    constexpr int KS = MF / 32;
    _Float16* Xh = (_Float16*)smem_;           // [64][KP]
    _Float16* Wz = Xh + 64 * KP;               // [NT*KS*64][8]
    const int t = threadIdx.x;

    // ---- stage W fragments (independent of gather) ----
    constexpr int WENT = NT * KS * 64;
    for (int idx = t; idx < WENT; idx += 256) {
        int lane = idx & 63, rest = idx >> 6;
        int ks = rest % KS, ntl = rest / KS;
        int kbase = ks * 32 + (lane >> 4) * 8;
        int col   = ntl * 16 + (lane & 15);
        union { float4 f4; _Float16 h[8]; } u;
#pragma unroll
        for (int j = 0; j < 8; ++j) u.h[j] = (_Float16)W[(kbase + j) * MF + col];
        *(float4*)(Wz + idx * 8) = u.f4;
    }

    // ---- agg phase: 16B/lane, L lanes per node ----
    constexpr int L      = MF / 8;         // c:8, s:4
    constexpr int NPW    = 64 / L;         // c:8, s:16
    constexpr int PASSES = 64 / (4 * NPW); // c:2, s:1
    const int lane = t & 63, wave = t >> 6;
    const int fq = lane & (L - 1), sub = lane / L;
    const float4* H4 = (const float4*)Hin;
    const float4* b4 = (const float4*)b;
    float bb[8];
    {
        float4 b0 = b4[fq * 2], b1 = b4[fq * 2 + 1];
        bb[0] = b0.x; bb[1] = b0.y; bb[2] = b0.z; bb[3] = b0.w;
        bb[4] = b1.x; bb[5] = b1.y; bb[6] = b1.z; bb[7] = b1.w;
    }
#pragma unroll
    for (int pass = 0; pass < PASSES; ++pass) {
        int ln   = (pass * 4 + wave) * NPW + sub;   // local row 0..63
        int node = bid * 64 + ln;
        if (node < N) {
            int j0 = off_g[node], j1 = off_g[node + 1];
            float acc[8];
            load8h(H4, (size_t)node * L + fq, acc);  // self-loop
            int j = j0;
            for (; j + 8 <= j1; j += 8) {
                int s0 = csr[j],     s1 = csr[j + 1], s2 = csr[j + 2], s3 = csr[j + 3];
                int s4 = csr[j + 4], s5 = csr[j + 5], s6 = csr[j + 6], s7 = csr[j + 7];
                float a0[8], a1[8], a2[8], a3[8], a4[8], a5[8], a6[8], a7[8];
                load8h(H4, (size_t)s0 * L + fq, a0);
                load8h(H4, (size_t)s1 * L + fq, a1);
                load8h(H4, (size_t)s2 * L + fq, a2);
                load8h(H4, (size_t)s3 * L + fq, a3);
                load8h(H4, (size_t)s4 * L + fq, a4);
                load8h(H4, (size_t)s5 * L + fq, a5);
                load8h(H4, (size_t)s6 * L + fq, a6);
                load8h(H4, (size_t)s7 * L + fq, a7);
#pragma unroll
                for (int f = 0; f < 8; ++f) {
                    float g1 = ((a0[f] + a1[f]) + a2[f]) + a3[f];
                    float g2 = ((a4[f] + a5[f]) + a6[f]) + a7[f];
                    acc[f] += g1 + g2;
                }
            }
            for (; j + 4 <= j1; j += 4) {
                int s0 = csr[j], s1 = csr[j + 1], s2 = csr[j + 2], s3 = csr[j + 3];
                float a0[8], a1[8], a2[8], a3[8];
                load8h(H4, (size_t)s0 * L + fq, a0);
                load8h(H4, (size_t)s1 * L + fq, a1);
                load8h(H4, (size_t)s2 * L + fq, a2);
                load8h(H4, (size_t)s3 * L + fq, a3);
#pragma unroll
                for (int f = 0; f < 8; ++f)
                    acc[f] += ((a0[f] + a1[f]) + a2[f]) + a3[f];
            }
            for (; j < j1; ++j) {
                float a0[8];
                load8h(H4, (size_t)csr[j] * L + fq, a0);
#pragma unroll
                for (int f = 0; f < 8; ++f) acc[f] += a0[f];
            }
            float dv = dinv_g[node];
            union { float4 f4; __half2 h2[4]; } o;
#pragma unroll
            for (int p2 = 0; p2 < 4; ++p2) {
                float vx = dv * acc[2 * p2]     + bb[2 * p2];
                float vy = dv * acc[2 * p2 + 1] + bb[2 * p2 + 1];
                o.h2[p2] = __floats2half2_rn(vx > 0.f ? vx : 0.f, vy > 0.f ? vy : 0.f);
            }
            *(float4*)(Xh + ln * KP + fq * 8) = o.f4;
        } else {
            *(float4*)(Xh + ln * KP + fq * 8) = make_float4(0.f, 0.f, 0.f, 0.f);
        }
    }
    __syncthreads();

    // ---- MFMA phase ----
    const int quad = lane >> 4, nl = lane & 15;
    const int rowA = wave * 16 + nl;
    v4f acc2[NT];
#pragma unroll
    for (int i = 0; i < NT; ++i) acc2[i] = (v4f){0.f, 0.f, 0.f, 0.f};
#pragma unroll
    for (int ks = 0; ks < KS; ++ks) {
        v8h av = *(const v8h*)(Xh + rowA * KP + ks * 32 + quad * 8);
#pragma unroll
        for (int ntl = 0; ntl < NT; ++ntl) {
            v8h bv = *(const v8h*)(Wz + ((ntl * KS + ks) * 64 + lane) * 8);
            acc2[ntl] = __builtin_amdgcn_mfma_f32_16x16x32_f16(av, bv, acc2[ntl], 0, 0, 0);
        }
    }
#pragma unroll
    for (int r = 0; r < 4; ++r) {
        int gr = bid * 64 + wave * 16 + quad * 4 + r;
        if (gr < N) {
            float dv = dinv_g[gr];
#pragma unroll
            for (int ntl = 0; ntl < NT; ++ntl)
                Hout[(size_t)gr * MF + ntl * 16 + nl] = __float2half(acc2[ntl][r] * dv);
        }
    }
}

// ---- plain aggregate (final layer): out = relu(dinv*(H[i]+sum H[src]) + b) ----
template <int M>
__device__ void agg_body(int bid, const __half* __restrict__ H,
                         const int* __restrict__ off_g,
                         const int* __restrict__ csr,
                         const float* __restrict__ dinv_g,
                         const float* __restrict__ b,
                         __half* __restrict__ out, int Nloc) {
    constexpr int L   = M / 4;   // lanes per node (4 halves each)
    constexpr int NPW = 64 / L;  // nodes per wave
    int lane = threadIdx.x & 63;
    int wave = threadIdx.x >> 6;
    int fq   = lane & (L - 1);
    int sub  = lane / L;
    int node = (bid * 4 + wave) * NPW + sub;
    if (node >= Nloc) return;
    const float2* H4 = (const float2*)H;
    int j0 = off_g[node], j1 = off_g[node + 1];
    float4 acc = load4h(H4, (size_t)node * L + fq);  // self-loop
    int j = j0;
    for (; j + 8 <= j1; j += 8) {
        int s0 = csr[j],     s1 = csr[j + 1], s2 = csr[j + 2], s3 = csr[j + 3];
        int s4 = csr[j + 4], s5 = csr[j + 5], s6 = csr[j + 6], s7 = csr[j + 7];
        float4 a0 = load4h(H4, (size_t)s0 * L + fq);
        float4 a1 = load4h(H4, (size_t)s1 * L + fq);
        float4 a2 = load4h(H4, (size_t)s2 * L + fq);
        float4 a3 = load4h(H4, (size_t)s3 * L + fq);
        float4 a4 = load4h(H4, (size_t)s4 * L + fq);
        float4 a5 = load4h(H4, (size_t)s5 * L + fq);
        float4 a6 = load4h(H4, (size_t)s6 * L + fq);
        float4 a7 = load4h(H4, (size_t)s7 * L + fq);
        acc.x += (a0.x + a1.x + a2.x + a3.x) + (a4.x + a5.x + a6.x + a7.x);
        acc.y += (a0.y + a1.y + a2.y + a3.y) + (a4.y + a5.y + a6.y + a7.y);
        acc.z += (a0.z + a1.z + a2.z + a3.z) + (a4.z + a5.z + a6.z + a7.z);
        acc.w += (a0.w + a1.w + a2.w + a3.w) + (a4.w + a5.w + a6.w + a7.w);
    }
    for (; j + 4 <= j1; j += 4) {
        int s0 = csr[j], s1 = csr[j + 1], s2 = csr[j + 2], s3 = csr[j + 3];
        float4 a0 = load4h(H4, (size_t)s0 * L + fq);
        float4 a1 = load4h(H4, (size_t)s1 * L + fq);
        float4 a2 = load4h(H4, (size_t)s2 * L + fq);
        float4 a3 = load4h(H4, (size_t)s3 * L + fq);
        acc.x += a0.x + a1.x + a2.x + a3.x;
        acc.y += a0.y + a1.y + a2.y + a3.y;
        acc.z += a0.z + a1.z + a2.z + a3.z;
        acc.w += a0.w + a1.w + a2.w + a3.w;
    }
    for (; j < j1; ++j) {
        float4 a = load4h(H4, (size_t)csr[j] * L + fq);
        acc.x += a.x; acc.y += a.y; acc.z += a.z; acc.w += a.w;
    }
    float  dv = dinv_g[node];
    float4 bb = ((const float4*)b)[fq];
    float  vx = dv * acc.x + bb.x;
    float  vy = dv * acc.y + bb.y;
    float  vz = dv * acc.z + bb.z;
    float  vw = dv * acc.w + bb.w;
    union { float2 f2; __half2 h2[2]; } o;
    o.h2[0] = __floats2half2_rn(vx > 0.f ? vx : 0.f, vy > 0.f ? vy : 0.f);
    o.h2[1] = __floats2half2_rn(vz > 0.f ? vz : 0.f, vw > 0.f ? vw : 0.f);
    ((float2*)out)[(size_t)node * L + fq] = o.f2;
}

// ---- two-side kernels ----
__global__ __launch_bounds__(256) void gemmBoth0(const float* __restrict__ Xc, const float* __restrict__ Wc,
                                                 __half* __restrict__ cH, int Nc,
                                                 const float* __restrict__ Xs, const float* __restrict__ Ws,
                                                 __half* __restrict__ sH, int Ns,
                                                 const float* __restrict__ dinv_all, int Nc_pad, int nbC) {
    __shared__ __align__(16) char smem[17408];
    if (blockIdx.x < nbC) gemm_mfma<64, 64, float>(blockIdx.x, Xc, Wc, dinv_all, cH, Nc, smem);
    else                  gemm_mfma<64, 32, float>(blockIdx.x - nbC, Xs, Ws, dinv_all + Nc_pad, sH, Ns, smem);
}

__global__ __launch_bounds__(256) void fusedBoth(
        const __half* __restrict__ cHin, __half* __restrict__ cHout,
        const float* __restrict__ Wc, const float* __restrict__ bc,
        const __half* __restrict__ sHin, __half* __restrict__ sHout,
        const float* __restrict__ Ws, const float* __restrict__ bs,
        const int* __restrict__ off_all, const int* __restrict__ csr_all,
        const float* __restrict__ dinv_all,
        int Nc, int Ns, int Nc_pad, int nbC) {
    __shared__ __align__(16) char smem[17408];
    if (blockIdx.x < nbC)
        fused_agg_gemm<64>(blockIdx.x, cHin, off_all, csr_all, dinv_all, bc, Wc, cHout, Nc, smem);
    else
        fused_agg_gemm<32>(blockIdx.x - nbC, sHin, off_all + Nc_pad, csr_all,
                           dinv_all + Nc_pad, bs, Ws, sHout, Ns, smem);
}

__global__ __launch_bounds__(256) void aggBoth(const __half* __restrict__ cH, const __half* __restrict__ sH,
                                               const int* __restrict__ off_all, const int* __restrict__ csr_all,
                                               const float* __restrict__ dinv_all,
                                               const float* __restrict__ bc, const float* __restrict__ bs,
                                               __half* __restrict__ outc, __half* __restrict__ outs,
                                               int Nc, int Ns, int Nc_pad, int nbC) {
    if (blockIdx.x < nbC)
        agg_body<64>(blockIdx.x, cH, off_all, csr_all, dinv_all, bc, outc, Nc);
    else
        agg_body<32>(blockIdx.x - nbC, sH, off_all + Nc_pad, csr_all,
                     dinv_all + Nc_pad, bs, outs, Ns);
}

// ---- fused pooling + MLP head (256 threads; 8B/lane vectorized pooling) ----
__device__ __forceinline__ int lbound(const int* __restrict__ a, int n, int key) {
    int lo = 0, hi = n;
    while (lo < hi) {
        int mid = (lo + hi) >> 1;
        if (a[mid] < key) lo = mid + 1; else hi = mid;
    }
    return lo;
}

__global__ __launch_bounds__(256) void poolDense(const __half* __restrict__ cX, const int* __restrict__ c_batch, int Nc,
                                                 const __half* __restrict__ sX, const int* __restrict__ s_batch, int Ns,
                                                 const float* __restrict__ Wd, const float* __restrict__ bd,
                                                 const float* __restrict__ Wo, const float* __restrict__ bo,
                                                 float* __restrict__ outv, float* __restrict__ embed) {
    __shared__ float e[192];
    __shared__ float red[2048];   // [16grp][64f] max + [16grp][64f] sum (c) / [32grp][32f] x2 (s)
    __shared__ float rs[128];
    int g = blockIdx.x, t = threadIdx.x;
    const float2* c4 = (const float2*)cX;   // 4 halves per entry, 16 per row
    const float2* s4 = (const float2*)sX;   // 4 halves per entry, 8 per row
    int clo = lbound(c_batch, Nc, g), chi = lbound(c_batch, Nc, g + 1);
    {   // c-pool: 16 feature-quads x 16 row-groups, 8B loads
        int q = t & 15, grp = t >> 4;
        float mx0 = 0.f, mx1 = 0.f, mx2 = 0.f, mx3 = 0.f;
        float sm0 = 0.f, sm1 = 0.f, sm2 = 0.f, sm3 = 0.f;
        for (int i = clo + grp; i < chi; i += 16) {
            float4 v = load4h(c4, (size_t)i * 16 + q);
            mx0 = fmaxf(mx0, v.x); sm0 += v.x;
            mx1 = fmaxf(mx1, v.y); sm1 += v.y;
            mx2 = fmaxf(mx2, v.z); sm2 += v.z;
            mx3 = fmaxf(mx3, v.w); sm3 += v.w;
        }
        // relu >= 0, so 0-init max is exact
        red[grp * 64 + q * 4 + 0]        = mx0;
        red[grp * 64 + q * 4 + 1]        = mx1;
        red[grp * 64 + q * 4 + 2]        = mx2;
        red[grp * 64 + q * 4 + 3]        = mx3;
        red[1024 + grp * 64 + q * 4 + 0] = sm0;
        red[1024 + grp * 64 + q * 4 + 1] = sm1;
        red[1024 + grp * 64 + q * 4 + 2] = sm2;
        red[1024 + grp * 64 + q * 4 + 3] = sm3;
    }
    __syncthreads();
    if (t < 64) {
        float m = red[t], s = red[1024 + t];
#pragma unroll
        for (int grp = 1; grp < 16; ++grp) {
            m = fmaxf(m, red[grp * 64 + t]);
            s += red[1024 + grp * 64 + t];
        }
        int cn = chi - clo;
        e[t]      = m;
        e[64 + t] = s / (float)(cn > 0 ? cn : 1);
    }
    __syncthreads();
    int slo = lbound(s_batch, Ns, g), shi = lbound(s_batch, Ns, g + 1);
    {   // s-pool: 8 feature-quads x 32 row-groups, 8B loads
        int q = t & 7, grp = t >> 3;
        float mx0 = 0.f, mx1 = 0.f, mx2 = 0.f, mx3 = 0.f;
        float sm0 = 0.f, sm1 = 0.f, sm2 = 0.f, sm3 = 0.f;
        for (int i = slo + grp; i < shi; i += 32) {
            float4 v = load4h(s4, (size_t)i * 8 + q);
            mx0 = fmaxf(mx0, v.x); sm0 += v.x;
            mx1 = fmaxf(mx1, v.y); sm1 += v.y;
            mx2 = fmaxf(mx2, v.z); sm2 += v.z;
            mx3 = fmaxf(mx3, v.w); sm3 += v.w;
        }
        red[grp * 32 + q * 4 + 0]        = mx0;
        red[grp * 32 + q * 4 + 1]        = mx1;
        red[grp * 32 + q * 4 + 2]        = mx2;
        red[grp * 32 + q * 4 + 3]        = mx3;
        red[1024 + grp * 32 + q * 4 + 0] = sm0;
        red[1024 + grp * 32 + q * 4 + 1] = sm1;
        red[1024 + grp * 32 + q * 4 + 2] = sm2;
        red[1024 + grp * 32 + q * 4 + 3] = sm3;
    }
    __syncthreads();
    if (t < 32) {
        float m = red[t], s = red[1024 + t];
#pragma unroll
        for (int grp = 1; grp < 32; ++grp) {
            m = fmaxf(m, red[grp * 32 + t]);
            s += red[1024 + grp * 32 + t];
        }
        int cn = shi - slo;
        e[128 + t] = m;
        e[160 + t] = s / (float)(cn > 0 ? cn : 1);
    }
    __syncthreads();
    if (t < 192) embed[(size_t)g * 192 + t] = e[t];
    if (t < 128) {
        float acc = bd[t];
        for (int k = 0; k < 192; ++k) acc += e[k] * Wd[k * 128 + t];
        float d = acc > 0.f ? acc : 0.f;
        rs[t] = d * Wo[t];
    }
    __syncthreads();
    for (int ofs = 64; ofs > 0; ofs >>= 1) {
        if (t < ofs) rs[t] += rs[t + ofs];
        __syncthreads();
    }
    if (t == 0) outv[g] = rs[0] + bo[0];
}

// ---------------------------------------------------------------------------

extern "C" void kernel_launch(void* const* d_in, const int* in_sizes, int n_in,
                              void* d_out, int out_size, void* d_ws, size_t ws_size,
                              hipStream_t stream) {
    const float* c       = (const float*)d_in[0];
    const int*   c_edge  = (const int*)d_in[1];
    const int*   c_batch = (const int*)d_in[2];
    const float* s       = (const float*)d_in[3];
    const int*   s_edge  = (const int*)d_in[4];
    const int*   s_batch = (const int*)d_in[5];
    const float* Wc0 = (const float*)d_in[6],  *bc0 = (const float*)d_in[7];
    const float* Wc1 = (const float*)d_in[8],  *bc1 = (const float*)d_in[9];
    const float* Wc2 = (const float*)d_in[10], *bc2 = (const float*)d_in[11];
    const float* Ws0 = (const float*)d_in[12], *bs0 = (const float*)d_in[13];
    const float* Ws1 = (const float*)d_in[14], *bs1 = (const float*)d_in[15];
    const float* Ws2 = (const float*)d_in[16], *bs2 = (const float*)d_in[17];
    const float* Wd  = (const float*)d_in[18], *bd  = (const float*)d_in[19];
    const float* Wo  = (const float*)d_in[20], *bo  = (const float*)d_in[21];

    const int Nc = in_sizes[0] / 64;
    const int Ec = in_sizes[1] / 2;
    const int Ns = in_sizes[3] / 64;
    const int Es = in_sizes[4] / 2;
    const int G  = out_size / 193;  // 2048
    const int Nc_pad   = cdiv(Nc, 512) * 512;
    const int Ns_pad   = cdiv(Ns, 512) * 512;
    const int Ntot_pad = Nc_pad + Ns_pad;
    const int Etot     = Ec + Es;
    const int nbuck    = Ntot_pad >> 9;

    // ---- workspace carve ----
    char* p = (char*)d_ws;
    auto  alloc = [&](size_t bytes) -> void* {
        void* r = (void*)p;
        p += (bytes + 255) & ~(size_t)255;
        return r;
    };
    int*      bucket_fill = (int*)alloc(512 * 4);
    int*      bucket_base = (int*)alloc(512 * 4);
    unsigned* pk          = (unsigned*)alloc((size_t)nbuck * BUCKET_CAP * 4);
    int*      off_all     = (int*)alloc(((size_t)Ntot_pad + 1) * 4);
    int*      csr_all     = (int*)alloc((size_t)Etot * 4);
    float*    dinv_all    = (float*)alloc((size_t)Ntot_pad * 4);
    __half*   bufC        = (__half*)alloc((size_t)Nc * 64 * 2);
    __half*   bufS        = (__half*)alloc((size_t)Ns * 32 * 2);
    __half*   cHa         = (__half*)alloc((size_t)Nc * 64 * 2);
    __half*   cHb         = (__half*)alloc((size_t)Nc * 64 * 2);
    __half*   sHa         = (__half*)alloc((size_t)Ns * 32 * 2);
    __half*   sHb         = (__half*)alloc((size_t)Ns * 32 * 2);

    float* outv  = (float*)d_out;  // [G]
    float* embed = outv + G;       // [G][192]

    const int nbGmC = cdiv(Nc, 64), nbGmS = cdiv(Ns, 64);
    const int nbFC  = cdiv(Nc, 64), nbFS  = cdiv(Ns, 64);
    const int nbAgC = Nc_pad / 16,  nbAgS = Ns_pad / 32;

    // 1) CSR build (bucketed, LDS atomics only)
    zero_int<<<cdiv(nbuck, 256), 256, 0, stream>>>(bucket_fill, nbuck);
    p1_partition<<<cdiv(Etot, P1_CHUNK), 256, 0, stream>>>(c_edge, Ec, s_edge, Es,
                                                           Nc_pad, Etot, nbuck, bucket_fill, pk);
    p2_scanbuckets<<<1, 512, 0, stream>>>(bucket_fill, nbuck, bucket_base, off_all, Ntot_pad, Etot);
    p3_build<<<nbuck, 512, 0, stream>>>(pk, bucket_fill, bucket_base,
                                        off_all, dinv_all, csr_all);

    // 2) layer-0 GEMMs (both sides)
    gemmBoth0<<<nbGmC + nbGmS, 256, 0, stream>>>(c, Wc0, cHa, Nc, s, Ws0, sHa, Ns,
                                                 dinv_all, Nc_pad, nbGmC);

    // 3) fused agg0+gemm1 (both sides): cHa->cHb, sHa->sHb
    fusedBoth<<<nbFC + nbFS, 256, 0, stream>>>(cHa, cHb, Wc1, bc0, sHa, sHb, Ws1, bs0,
                                               off_all, csr_all, dinv_all,
                                               Nc, Ns, Nc_pad, nbFC);
    // 4) fused agg1+gemm2 (both sides): cHb->cHa, sHb->sHa
    fusedBoth<<<nbFC + nbFS, 256, 0, stream>>>(cHb, cHa, Wc2, bc1, sHb, sHa, Ws2, bs1,
                                               off_all, csr_all, dinv_all,
                                               Nc, Ns, Nc_pad, nbFC);

    // 5) final aggregation (both sides) -> bufC/bufS
    aggBoth<<<nbAgC + nbAgS, 256, 0, stream>>>(cHa, sHa, off_all, csr_all, dinv_all,
                                               bc2, bs2, bufC, bufS, Nc, Ns, Nc_pad, nbAgC);

    // 6) fused pooling + MLP
    poolDense<<<G, 256, 0, stream>>>(bufC, c_batch, Nc, bufS, s_batch, Ns,
                                     Wd, bd, Wo, bo, outv, embed);
}